// Round 1
// baseline (3538.728 us; speedup 1.0000x reference)
//
#include <hip/hip_runtime.h>
#include <hip/hip_bf16.h>
#include <math.h>

// Problem constants
#define TDEC  32
#define TCTX  32
#define BATCH 128
#define HSZ   1024
#define ESZ   1024
#define CSZ   1024
#define G4    4096          // 4*H
#define MROWS 4096          // TDEC*BATCH

__device__ __forceinline__ float sigmoidf_(float x) {
    return 1.0f / (1.0f + __expf(-x));
}
__device__ __forceinline__ float tanhf_(float x) {
    x = fminf(fmaxf(x, -15.0f), 15.0f);
    float e = __expf(2.0f * x);
    return (e - 1.0f) / (e + 1.0f);
}

// C[m,n] = sum_k A[am,k]*W[n,k] (+b1[n]) (+b2[n]) (+Cadd[m,n])
// am = gather ? gather[m] : m.   A: (M,K) row-major (or gathered rows of a
// bigger table), W: (N,K) row-major  ->  "NT" gemm, both operands K-contiguous.
template <int BM, int BN, int BK, int TM, int TN>
__launch_bounds__((BM / TM) * (BN / TN))
__global__ void gemm_nt(const float* __restrict__ A, const float* __restrict__ W,
                        const float* __restrict__ b1, const float* __restrict__ b2,
                        const float* __restrict__ Cadd, const int* __restrict__ gather,
                        float* __restrict__ C, int M, int N, int K)
{
    constexpr int NT = (BM / TM) * (BN / TN);
    static_assert(NT == 256, "expect 256 threads");
    __shared__ float As[BM][BK + 1];
    __shared__ float Ws[BN][BK + 1];

    const int m0 = blockIdx.y * BM;
    const int n0 = blockIdx.x * BN;
    const int tid = threadIdx.x;
    const int tx = tid % (BN / TN);
    const int ty = tid / (BN / TN);

    float acc[TM][TN];
#pragma unroll
    for (int i = 0; i < TM; i++)
#pragma unroll
        for (int j = 0; j < TN; j++) acc[i][j] = 0.0f;

    for (int k0 = 0; k0 < K; k0 += BK) {
        // ---- load A tile (BM x BK) as float4 ----
        constexpr int A4 = BM * BK / 4;
#pragma unroll
        for (int l = 0; l < A4; l += NT) {
            int idx = l + tid;
            if (A4 >= NT || idx < A4) {
                int r = idx / (BK / 4);
                int cq = idx % (BK / 4);
                int gm = m0 + r;
                int arow = gather ? gather[gm] : gm;
                const float4 v = *reinterpret_cast<const float4*>(
                    &A[(size_t)arow * K + k0 + cq * 4]);
                As[r][cq * 4 + 0] = v.x;
                As[r][cq * 4 + 1] = v.y;
                As[r][cq * 4 + 2] = v.z;
                As[r][cq * 4 + 3] = v.w;
            }
        }
        // ---- load W tile (BN x BK) as float4 ----
        constexpr int W4 = BN * BK / 4;
#pragma unroll
        for (int l = 0; l < W4; l += NT) {
            int idx = l + tid;
            if (W4 >= NT || idx < W4) {
                int r = idx / (BK / 4);
                int cq = idx % (BK / 4);
                const float4 v = *reinterpret_cast<const float4*>(
                    &W[(size_t)(n0 + r) * K + k0 + cq * 4]);
                Ws[r][cq * 4 + 0] = v.x;
                Ws[r][cq * 4 + 1] = v.y;
                Ws[r][cq * 4 + 2] = v.z;
                Ws[r][cq * 4 + 3] = v.w;
            }
        }
        __syncthreads();

#pragma unroll
        for (int kk = 0; kk < BK; kk++) {
            float a[TM], w[TN];
#pragma unroll
            for (int i = 0; i < TM; i++) a[i] = As[ty * TM + i][kk];
#pragma unroll
            for (int j = 0; j < TN; j++) w[j] = Ws[tx * TN + j][kk];
#pragma unroll
            for (int i = 0; i < TM; i++)
#pragma unroll
                for (int j = 0; j < TN; j++)
                    acc[i][j] = fmaf(a[i], w[j], acc[i][j]);
        }
        __syncthreads();
    }

#pragma unroll
    for (int i = 0; i < TM; i++) {
        int m = m0 + ty * TM + i;
#pragma unroll
        for (int j = 0; j < TN; j++) {
            int n = n0 + tx * TN + j;
            float v = acc[i][j];
            if (b1) v += b1[n];
            if (b2) v += b2[n];
            if (Cadd) v += Cadd[(size_t)m * N + n];
            C[(size_t)m * N + n] = v;
        }
    }
}

// gates g: (B, 4H) with PyTorch order i,f,g,o.  c in/out (B,H).  h out (B,H).
__global__ void lstm_update(const float* __restrict__ g, float* __restrict__ c,
                            float* __restrict__ h)
{
    int idx = blockIdx.x * blockDim.x + threadIdx.x;
    if (idx >= BATCH * HSZ) return;
    int b = idx >> 10;          // /HSZ
    int j = idx & (HSZ - 1);
    const float* gb = g + (size_t)b * G4;
    float gi = gb[j];
    float gf = gb[HSZ + j];
    float gg = gb[2 * HSZ + j];
    float go = gb[3 * HSZ + j];
    float cn = sigmoidf_(gf) * c[idx] + sigmoidf_(gi) * tanhf_(gg);
    c[idx] = cn;
    h[idx] = sigmoidf_(go) * tanhf_(cn);
}

// vn = norm_scalar * v / ||v||   (one block of 1024 threads)
__global__ void prep_vn(const float* __restrict__ v, const float* __restrict__ ns,
                        float* __restrict__ vn)
{
    __shared__ float red[16];
    __shared__ float total;
    int tid = threadIdx.x;       // 1024
    float x = v[tid];
    float s = x * x;
#pragma unroll
    for (int o = 32; o > 0; o >>= 1) s += __shfl_down(s, o, 64);
    if ((tid & 63) == 0) red[tid >> 6] = s;
    __syncthreads();
    if (tid == 0) {
        float t = 0.0f;
#pragma unroll
        for (int i = 0; i < 16; i++) t += red[i];
        total = sqrtf(t);
    }
    __syncthreads();
    vn[tid] = ns[0] * x / total;
}

// One block per (b, tq).  256 threads, each owns 4 hidden dims.
// scores[tk] = sum_u vn[u]*tanh(q[u]+k[u]+bias[u]); mask; softmax; PV.
__launch_bounds__(256)
__global__ void attn_kernel(const float* __restrict__ Q, const float* __restrict__ Km,
                            const float* __restrict__ vn, const float* __restrict__ abias,
                            const float* __restrict__ ctx, const int* __restrict__ ctx_len,
                            float* __restrict__ out)
{
    int bid = blockIdx.x;
    int b = bid >> 5;            // / TDEC
    int tq = bid & 31;
    int tid = threadIdx.x;       // 256

    float4 qv = *reinterpret_cast<const float4*>(&Q[((size_t)tq * BATCH + b) * HSZ + tid * 4]);
    float4 bv = *reinterpret_cast<const float4*>(&abias[tid * 4]);
    float4 vv = *reinterpret_cast<const float4*>(&vn[tid * 4]);
    qv.x += bv.x; qv.y += bv.y; qv.z += bv.z; qv.w += bv.w;

    __shared__ float sc[TCTX];
    __shared__ float wred[4];

    for (int tk = 0; tk < TCTX; tk++) {
        float4 kv = *reinterpret_cast<const float4*>(&Km[((size_t)tk * BATCH + b) * HSZ + tid * 4]);
        float p = vv.x * tanhf_(qv.x + kv.x)
                + vv.y * tanhf_(qv.y + kv.y)
                + vv.z * tanhf_(qv.z + kv.z)
                + vv.w * tanhf_(qv.w + kv.w);
#pragma unroll
        for (int o = 32; o > 0; o >>= 1) p += __shfl_down(p, o, 64);
        if ((tid & 63) == 0) wred[tid >> 6] = p;
        __syncthreads();
        if (tid == 0) sc[tk] = wred[0] + wred[1] + wred[2] + wred[3];
        __syncthreads();
    }

    // masked softmax over 32 keys, done in the first half-wave
    int cl = ctx_len[b];
    if (tid < 32) {
        float s = sc[tid];
        if (tid >= cl) s = -65504.0f;
        float m = s;
#pragma unroll
        for (int o = 16; o > 0; o >>= 1) m = fmaxf(m, __shfl_xor(m, o, 32));
        float e = __expf(s - m);
        float d = e;
#pragma unroll
        for (int o = 16; o > 0; o >>= 1) d += __shfl_xor(d, o, 32);
        sc[tid] = e / d;
    }
    __syncthreads();

    float4 acc = {0.f, 0.f, 0.f, 0.f};
    for (int tk = 0; tk < TCTX; tk++) {
        float w = sc[tk];
        float4 cv = *reinterpret_cast<const float4*>(&ctx[((size_t)tk * BATCH + b) * CSZ + tid * 4]);
        acc.x = fmaf(w, cv.x, acc.x);
        acc.y = fmaf(w, cv.y, acc.y);
        acc.z = fmaf(w, cv.z, acc.z);
        acc.w = fmaf(w, cv.w, acc.w);
    }
    *reinterpret_cast<float4*>(&out[((size_t)tq * BATCH + b) * CSZ + tid * 4]) = acc;
}

extern "C" void kernel_launch(void* const* d_in, const int* in_sizes, int n_in,
                              void* d_out, int out_size, void* d_ws, size_t ws_size,
                              hipStream_t stream)
{
    const int*   ctx_len     = (const int*)d_in[0];
    const int*   tokens      = (const int*)d_in[1];   // (TDEC, BATCH) -> m = t*B+b
    const float* context     = (const float*)d_in[2]; // (TCTX, BATCH, C)
    const float* emb_table   = (const float*)d_in[3]; // (V, E)
    const float* W_ih        = (const float*)d_in[4]; // (4H, E)
    const float* W_hh        = (const float*)d_in[5]; // (4H, H)
    const float* b_ih        = (const float*)d_in[6];
    const float* b_hh        = (const float*)d_in[7];
    const float* Wq          = (const float*)d_in[8]; // (H, H)
    const float* Wk          = (const float*)d_in[9]; // (H, C)
    const float* v_att       = (const float*)d_in[10];
    const float* att_bias    = (const float*)d_in[11];
    const float* norm_scalar = (const float*)d_in[12];

    float* out      = (float*)d_out;
    float* attn_out = out;                                  // (TDEC,B,C)
    float* rnn_out  = out + (size_t)TDEC * BATCH * CSZ;     // (TDEC,B,H)

    // workspace layout (floats); total ~103 MB
    float* ws   = (float*)d_ws;
    float* xp   = ws;                                   // MROWS*G4   = 16777216
    float* gbuf = xp + (size_t)MROWS * G4;              // BATCH*G4   =   524288
    float* cst  = gbuf + (size_t)BATCH * G4;            // BATCH*H    =   131072
    float* qbuf = cst + (size_t)BATCH * HSZ;            // MROWS*H    =  4194304
    float* kbuf = qbuf + (size_t)MROWS * HSZ;           // MROWS*H    =  4194304
    float* vn   = kbuf + (size_t)MROWS * HSZ;           // 1024

    // c0 = 0
    hipMemsetAsync(cst, 0, (size_t)BATCH * HSZ * sizeof(float), stream);
    prep_vn<<<1, 1024, 0, stream>>>(v_att, norm_scalar, vn);

    // xp = emb_table[tokens] @ W_ih^T + b_ih + b_hh     (4096 x 4096 x 1024)
    {
        dim3 grid(G4 / 64, MROWS / 64);
        gemm_nt<64, 64, 16, 4, 4><<<grid, 256, 0, stream>>>(
            emb_table, W_ih, b_ih, b_hh, nullptr, tokens, xp, MROWS, G4, ESZ);
    }

    // LSTM.  t=0: h0=0 so gates = xp[0] directly.
    lstm_update<<<(BATCH * HSZ) / 256, 256, 0, stream>>>(xp, cst, rnn_out);
    for (int t = 1; t < TDEC; t++) {
        dim3 grid(G4 / 64, BATCH / 32);
        gemm_nt<32, 64, 16, 2, 4><<<grid, 256, 0, stream>>>(
            rnn_out + (size_t)(t - 1) * BATCH * HSZ, W_hh,
            nullptr, nullptr, xp + (size_t)t * BATCH * G4, nullptr,
            gbuf, BATCH, G4, HSZ);
        lstm_update<<<(BATCH * HSZ) / 256, 256, 0, stream>>>(
            gbuf, cst, rnn_out + (size_t)t * BATCH * HSZ);
    }

    // q = rnn_out @ Wq^T  (4096 x 1024 x 1024);  k = context @ Wk^T
    {
        dim3 grid(HSZ / 64, MROWS / 64);
        gemm_nt<64, 64, 16, 4, 4><<<grid, 256, 0, stream>>>(
            rnn_out, Wq, nullptr, nullptr, nullptr, nullptr, qbuf, MROWS, HSZ, HSZ);
        gemm_nt<64, 64, 16, 4, 4><<<grid, 256, 0, stream>>>(
            context, Wk, nullptr, nullptr, nullptr, nullptr, kbuf, MROWS, HSZ, CSZ);
    }

    // fused scores + masked softmax + attention output
    attn_kernel<<<BATCH * TDEC, 256, 0, stream>>>(
        qbuf, kbuf, vn, att_bias, context, ctx_len, attn_out);
}

// Round 2
// 974.580 us; speedup vs baseline: 3.6310x; 3.6310x over previous
//
#include <hip/hip_runtime.h>
#include <hip/hip_bf16.h>
#include <math.h>

#define TDEC  32
#define TCTX  32
#define BATCH 128
#define HSZ   1024
#define ESZ   1024
#define CSZ   1024
#define G4    4096
#define MROWS 4096

typedef __attribute__((ext_vector_type(8))) __bf16 bf16x8;
typedef __attribute__((ext_vector_type(4))) float  f32x4;

__device__ __forceinline__ float sigmoidf_(float x) {
    return 1.0f / (1.0f + __expf(-x));
}
__device__ __forceinline__ float tanhf_(float x) {
    x = fminf(fmaxf(x, -15.0f), 15.0f);
    float e = __expf(2.0f * x);
    return (e - 1.0f) / (e + 1.0f);
}
__device__ __forceinline__ unsigned short f2bf(float x) {
    unsigned int u = __float_as_uint(x);
    unsigned int r = (u + 0x7FFFu + ((u >> 16) & 1u)) >> 16;
    return (unsigned short)r;
}
__device__ __forceinline__ float bf2f(unsigned short h) {
    return __uint_as_float(((unsigned int)h) << 16);
}
__device__ __forceinline__ uint4 pack8(float4 a, float4 b) {
    uint4 r;
    r.x = (unsigned)f2bf(a.x) | ((unsigned)f2bf(a.y) << 16);
    r.y = (unsigned)f2bf(a.z) | ((unsigned)f2bf(a.w) << 16);
    r.z = (unsigned)f2bf(b.x) | ((unsigned)f2bf(b.y) << 16);
    r.w = (unsigned)f2bf(b.z) | ((unsigned)f2bf(b.w) << 16);
    return r;
}

// ---------------------------------------------------------------------------
// C[m,n] = sum_k A[am,k] * B[n,k]  (NT gemm), MFMA bf16, 128x128 tile, BK=32.
// AGF: A is fp32 with row-gather (embedding path), converted to bf16 in-flight.
// OUTB: write bf16 output, else fp32.  Optional bias1+bias2 (fp32, per col).
// ---------------------------------------------------------------------------
template <bool AGF, bool OUTB>
__launch_bounds__(256)
__global__ void gemm_bf16(const void* __restrict__ Ap,
                          const unsigned short* __restrict__ Bw,
                          const float* __restrict__ bias1, const float* __restrict__ bias2,
                          const int* __restrict__ gather, void* __restrict__ Cout,
                          int M, int N, int K)
{
    __shared__ __align__(16) unsigned short As[128 * 32];
    __shared__ __align__(16) unsigned short Bs[128 * 32];

    const int tid  = threadIdx.x;
    const int lane = tid & 63;
    const int w    = tid >> 6;
    const int m0   = blockIdx.y * 128;
    const int n0   = blockIdx.x * 128;
    const int srow = tid >> 2;          // 0..63
    const int slot = tid & 3;           // 16B slot within 64B row

    const unsigned short* pB0 = Bw + (size_t)(n0 + srow) * K + slot * 8;
    const unsigned short* pB1 = Bw + (size_t)(n0 + srow + 64) * K + slot * 8;

    const float* pAf0 = nullptr; const float* pAf1 = nullptr;
    const unsigned short* pAb0 = nullptr; const unsigned short* pAb1 = nullptr;
    if constexpr (AGF) {
        const float* Af = (const float*)Ap;
        const int r0 = gather[m0 + srow];
        const int r1 = gather[m0 + srow + 64];
        pAf0 = Af + (size_t)r0 * K + slot * 8;
        pAf1 = Af + (size_t)r1 * K + slot * 8;
    } else {
        const unsigned short* Ab = (const unsigned short*)Ap;
        pAb0 = Ab + (size_t)(m0 + srow) * K + slot * 8;
        pAb1 = Ab + (size_t)(m0 + srow + 64) * K + slot * 8;
    }

    uint4* dA0 = (uint4*)&As[srow * 32 + slot * 8];
    uint4* dA1 = (uint4*)&As[(srow + 64) * 32 + slot * 8];
    uint4* dB0 = (uint4*)&Bs[srow * 32 + slot * 8];
    uint4* dB1 = (uint4*)&Bs[(srow + 64) * 32 + slot * 8];

    const int fr = lane & 15;
    const int fk = (lane >> 4) * 8;
    const int wm = (w >> 1) * 64;
    const int wn = (w & 1) * 64;

    f32x4 acc[4][4];
    const f32x4 zero4 = {0.f, 0.f, 0.f, 0.f};
#pragma unroll
    for (int i = 0; i < 4; i++)
#pragma unroll
        for (int j = 0; j < 4; j++) acc[i][j] = zero4;

    uint4 rA0, rA1, rB0, rB1;
    float4 fA00, fA01, fA10, fA11;

    // prologue loads (tile k0 = 0)
    if constexpr (AGF) {
        fA00 = *(const float4*)(pAf0);  fA01 = *(const float4*)(pAf0 + 4);
        fA10 = *(const float4*)(pAf1);  fA11 = *(const float4*)(pAf1 + 4);
    } else {
        rA0 = *(const uint4*)(pAb0);    rA1 = *(const uint4*)(pAb1);
    }
    rB0 = *(const uint4*)(pB0);  rB1 = *(const uint4*)(pB1);

    for (int k0 = 0; k0 < K; k0 += 32) {
        if constexpr (AGF) { *dA0 = pack8(fA00, fA01); *dA1 = pack8(fA10, fA11); }
        else               { *dA0 = rA0;               *dA1 = rA1; }
        *dB0 = rB0; *dB1 = rB1;
        __syncthreads();

        const int kn = k0 + 32;
        if (kn < K) {   // prefetch next tile while MFMAs run
            if constexpr (AGF) {
                fA00 = *(const float4*)(pAf0 + kn);  fA01 = *(const float4*)(pAf0 + kn + 4);
                fA10 = *(const float4*)(pAf1 + kn);  fA11 = *(const float4*)(pAf1 + kn + 4);
            } else {
                rA0 = *(const uint4*)(pAb0 + kn);    rA1 = *(const uint4*)(pAb1 + kn);
            }
            rB0 = *(const uint4*)(pB0 + kn);  rB1 = *(const uint4*)(pB1 + kn);
        }

        bf16x8 a[4], b[4];
#pragma unroll
        for (int i = 0; i < 4; i++) a[i] = *(const bf16x8*)&As[(wm + i * 16 + fr) * 32 + fk];
#pragma unroll
        for (int j = 0; j < 4; j++) b[j] = *(const bf16x8*)&Bs[(wn + j * 16 + fr) * 32 + fk];
#pragma unroll
        for (int i = 0; i < 4; i++)
#pragma unroll
            for (int j = 0; j < 4; j++)
                acc[i][j] = __builtin_amdgcn_mfma_f32_16x16x32_bf16(a[i], b[j], acc[i][j], 0, 0, 0);
        __syncthreads();
    }

    // epilogue: C/D layout col=lane&15, row=(lane>>4)*4+reg  [m89-verified]
    const int orow = (lane >> 4) * 4;
#pragma unroll
    for (int j = 0; j < 4; j++) {
        const int col = n0 + wn + j * 16 + fr;
        float badd = 0.f;
        if (bias1) badd += bias1[col];
        if (bias2) badd += bias2[col];
#pragma unroll
        for (int i = 0; i < 4; i++) {
#pragma unroll
            for (int r = 0; r < 4; r++) {
                const int row = m0 + wm + i * 16 + orow + r;
                const float v = acc[i][j][r] + badd;
                if constexpr (OUTB)
                    ((unsigned short*)Cout)[(size_t)row * N + col] = f2bf(v);
                else
                    ((float*)Cout)[(size_t)row * N + col] = v;
            }
        }
    }
}

// ---------------------------------------------------------------------------
// Fused LSTM step: gates = h_prev @ W_hh^T (MFMA, wave w = gate w) + xp[t];
// then cell update.  Grid (32, 2): 32 hidden-chunks x 2 batch-halves.
// ---------------------------------------------------------------------------
__launch_bounds__(256)
__global__ void lstm_step(const unsigned short* __restrict__ hprev,  // (128,1024) bf16
                          const unsigned short* __restrict__ Whh,    // (4096,1024) bf16
                          const float* __restrict__ xp_t,            // (128,4096) fp32
                          float* __restrict__ c,                     // (128,1024) state
                          float* __restrict__ hf,                    // fp32 out
                          unsigned short* __restrict__ hb)           // bf16 out
{
    __shared__ __align__(16) unsigned short As[64 * 32];
    __shared__ __align__(16) unsigned short Bs[128 * 32];
    __shared__ float Gs[4][64][32];

    const int tid  = threadIdx.x;
    const int lane = tid & 63;
    const int w    = tid >> 6;
    const int m0   = blockIdx.y * 64;     // batch rows
    const int j0   = blockIdx.x * 32;     // hidden cols per gate

    const int srow = tid >> 2, slot = tid & 3;
    const unsigned short* pA = hprev + (size_t)(m0 + srow) * HSZ + slot * 8;
    const int lr1 = srow + 64;
    const unsigned short* pB0 = Whh + (size_t)((srow >> 5) * HSZ + j0 + (srow & 31)) * HSZ + slot * 8;
    const unsigned short* pB1 = Whh + (size_t)((lr1 >> 5) * HSZ + j0 + (lr1 & 31)) * HSZ + slot * 8;

    uint4* dA  = (uint4*)&As[srow * 32 + slot * 8];
    uint4* dB0 = (uint4*)&Bs[srow * 32 + slot * 8];
    uint4* dB1 = (uint4*)&Bs[lr1 * 32 + slot * 8];

    const int fr = lane & 15, fk = (lane >> 4) * 8;

    f32x4 acc[4][2];
    const f32x4 zero4 = {0.f, 0.f, 0.f, 0.f};
#pragma unroll
    for (int i = 0; i < 4; i++) { acc[i][0] = zero4; acc[i][1] = zero4; }

    uint4 rA = *(const uint4*)pA;
    uint4 rB0 = *(const uint4*)pB0;
    uint4 rB1 = *(const uint4*)pB1;

    for (int k0 = 0; k0 < HSZ; k0 += 32) {
        *dA = rA; *dB0 = rB0; *dB1 = rB1;
        __syncthreads();
        const int kn = k0 + 32;
        if (kn < HSZ) {
            rA  = *(const uint4*)(pA + kn);
            rB0 = *(const uint4*)(pB0 + kn);
            rB1 = *(const uint4*)(pB1 + kn);
        }
        bf16x8 a[4], b[2];
#pragma unroll
        for (int i = 0; i < 4; i++) a[i] = *(const bf16x8*)&As[(i * 16 + fr) * 32 + fk];
#pragma unroll
        for (int j = 0; j < 2; j++) b[j] = *(const bf16x8*)&Bs[(w * 32 + j * 16 + fr) * 32 + fk];
#pragma unroll
        for (int i = 0; i < 4; i++)
#pragma unroll
            for (int j = 0; j < 2; j++)
                acc[i][j] = __builtin_amdgcn_mfma_f32_16x16x32_bf16(a[i], b[j], acc[i][j], 0, 0, 0);
        __syncthreads();
    }

    const int orow = (lane >> 4) * 4;
#pragma unroll
    for (int i = 0; i < 4; i++)
#pragma unroll
        for (int j = 0; j < 2; j++)
#pragma unroll
            for (int r = 0; r < 4; r++)
                Gs[w][i * 16 + orow + r][j * 16 + fr] = acc[i][j][r];
    __syncthreads();

    // combine gates + cell update: 8 elems / thread
#pragma unroll
    for (int u = 0; u < 8; u++) {
        const int idx = u * 256 + tid;
        const int row = idx >> 5, col = idx & 31;
        const int bi = m0 + row, hj = j0 + col;
        const float* xr = xp_t + (size_t)bi * G4 + hj;
        const float gi = Gs[0][row][col] + xr[0];
        const float gf = Gs[1][row][col] + xr[HSZ];
        const float gg = Gs[2][row][col] + xr[2 * HSZ];
        const float go = Gs[3][row][col] + xr[3 * HSZ];
        const size_t ci = (size_t)bi * HSZ + hj;
        const float cn = sigmoidf_(gf) * c[ci] + sigmoidf_(gi) * tanhf_(gg);
        c[ci] = cn;
        const float h = sigmoidf_(go) * tanhf_(cn);
        hf[ci] = h;
        hb[ci] = f2bf(h);
    }
}

// t = 0: h0 = c0 = 0 -> gates = xp[0]
__global__ void lstm0(const float* __restrict__ xp0, float* __restrict__ c,
                      float* __restrict__ hf, unsigned short* __restrict__ hb)
{
    const int id = blockIdx.x * 256 + threadIdx.x;     // 16384 threads
    const int b = id >> 7, j8 = (id & 127) * 8;
    const float* g = xp0 + (size_t)b * G4 + j8;
    float gi[8], gf[8], gg[8], go[8];
#pragma unroll
    for (int e = 0; e < 8; e++) {
        gi[e] = g[e];
        gf[e] = g[HSZ + e];
        gg[e] = g[2 * HSZ + e];
        go[e] = g[3 * HSZ + e];
    }
    (void)gf;
    const size_t base = (size_t)b * HSZ + j8;
#pragma unroll
    for (int e = 0; e < 8; e++) {
        const float cn = sigmoidf_(gi[e]) * tanhf_(gg[e]);   // f-gate * 0 drops
        c[base + e] = cn;
        const float h = sigmoidf_(go[e]) * tanhf_(cn);
        hf[base + e] = h;
        hb[base + e] = f2bf(h);
    }
}

__global__ void cvt_f32_bf16(const float* __restrict__ in, unsigned short* __restrict__ out, int n8)
{
    const int id = blockIdx.x * 256 + threadIdx.x;
    if (id >= n8) return;
    const float4 a = *(const float4*)(in + (size_t)id * 8);
    const float4 b = *(const float4*)(in + (size_t)id * 8 + 4);
    *(uint4*)(out + (size_t)id * 8) = pack8(a, b);
}

__global__ void prep_vn(const float* __restrict__ v, const float* __restrict__ ns,
                        float* __restrict__ vn)
{
    __shared__ float red[16];
    __shared__ float total;
    const int tid = threadIdx.x;     // 1024
    const float x = v[tid];
    float s = x * x;
#pragma unroll
    for (int o = 32; o > 0; o >>= 1) s += __shfl_down(s, o, 64);
    if ((tid & 63) == 0) red[tid >> 6] = s;
    __syncthreads();
    if (tid == 0) {
        float t = 0.f;
#pragma unroll
        for (int i = 0; i < 16; i++) t += red[i];
        total = sqrtf(t);
    }
    __syncthreads();
    vn[tid] = ns[0] * x / total;
}

// One block per (b, tq); q/k/ctx in bf16.
__launch_bounds__(256)
__global__ void attn_kernel(const unsigned short* __restrict__ Q,
                            const unsigned short* __restrict__ Km,
                            const float* __restrict__ vn, const float* __restrict__ abias,
                            const unsigned short* __restrict__ ctx,
                            const int* __restrict__ ctx_len, float* __restrict__ out)
{
    const int bid = blockIdx.x;
    const int b = bid >> 5, tq = bid & 31, tid = threadIdx.x;

    const ushort4 qu = *(const ushort4*)&Q[((size_t)tq * BATCH + b) * HSZ + tid * 4];
    const float4 bv = *(const float4*)&abias[tid * 4];
    const float4 vv = *(const float4*)&vn[tid * 4];
    const float q0 = bf2f(qu.x) + bv.x, q1 = bf2f(qu.y) + bv.y;
    const float q2 = bf2f(qu.z) + bv.z, q3 = bf2f(qu.w) + bv.w;

    __shared__ float sc[TCTX];
    __shared__ float wred[4];

    for (int tk = 0; tk < TCTX; tk++) {
        const ushort4 ku = *(const ushort4*)&Km[((size_t)tk * BATCH + b) * HSZ + tid * 4];
        float p = vv.x * tanhf_(q0 + bf2f(ku.x))
                + vv.y * tanhf_(q1 + bf2f(ku.y))
                + vv.z * tanhf_(q2 + bf2f(ku.z))
                + vv.w * tanhf_(q3 + bf2f(ku.w));
#pragma unroll
        for (int o = 32; o > 0; o >>= 1) p += __shfl_down(p, o, 64);
        if ((tid & 63) == 0) wred[tid >> 6] = p;
        __syncthreads();
        if (tid == 0) sc[tk] = wred[0] + wred[1] + wred[2] + wred[3];
        __syncthreads();
    }

    const int cl = ctx_len[b];
    if (tid < 32) {
        float s = sc[tid];
        if (tid >= cl) s = -65504.0f;
        float m = s;
#pragma unroll
        for (int o = 16; o > 0; o >>= 1) m = fmaxf(m, __shfl_xor(m, o, 32));
        const float e = __expf(s - m);
        float d = e;
#pragma unroll
        for (int o = 16; o > 0; o >>= 1) d += __shfl_xor(d, o, 32);
        sc[tid] = e / d;
    }
    __syncthreads();

    float4 acc = {0.f, 0.f, 0.f, 0.f};
    for (int tk = 0; tk < TCTX; tk++) {
        const float wgt = sc[tk];
        const ushort4 cu = *(const ushort4*)&ctx[((size_t)tk * BATCH + b) * CSZ + tid * 4];
        acc.x = fmaf(wgt, bf2f(cu.x), acc.x);
        acc.y = fmaf(wgt, bf2f(cu.y), acc.y);
        acc.z = fmaf(wgt, bf2f(cu.z), acc.z);
        acc.w = fmaf(wgt, bf2f(cu.w), acc.w);
    }
    *reinterpret_cast<float4*>(&out[((size_t)tq * BATCH + b) * CSZ + tid * 4]) = acc;
}

extern "C" void kernel_launch(void* const* d_in, const int* in_sizes, int n_in,
                              void* d_out, int out_size, void* d_ws, size_t ws_size,
                              hipStream_t stream)
{
    const int*   ctx_len     = (const int*)d_in[0];
    const int*   tokens      = (const int*)d_in[1];
    const float* context     = (const float*)d_in[2];
    const float* emb_table   = (const float*)d_in[3];
    const float* W_ih        = (const float*)d_in[4];
    const float* W_hh        = (const float*)d_in[5];
    const float* b_ih        = (const float*)d_in[6];
    const float* b_hh        = (const float*)d_in[7];
    const float* Wq          = (const float*)d_in[8];
    const float* Wk          = (const float*)d_in[9];
    const float* v_att       = (const float*)d_in[10];
    const float* att_bias    = (const float*)d_in[11];
    const float* norm_scalar = (const float*)d_in[12];

    float* out      = (float*)d_out;
    float* attn_out = out;
    float* rnn_out  = out + (size_t)TDEC * BATCH * CSZ;

    // workspace layout (bytes). xp region (67.1 MB) is reused for q/k/Wq/Wk
    // after the LSTM finishes.  Peak 101.2 MB (round-1 proved >=103 MB works).
    char* W = (char*)d_ws;
    float*          xp     = (float*)W;                          // 16777216 f32
    unsigned short* q_bf   = (unsigned short*)W;                 // overlay in xp
    unsigned short* k_bf   = (unsigned short*)(W + 8388608);     // overlay
    unsigned short* Wq_bf  = (unsigned short*)(W + 16777216);    // overlay
    unsigned short* Wk_bf  = (unsigned short*)(W + 18874368);    // overlay
    unsigned short* Wih_bf = (unsigned short*)(W + 67108864);
    unsigned short* Whh_bf = (unsigned short*)(W + 75497472);
    unsigned short* ctx_bf = (unsigned short*)(W + 83886080);
    unsigned short* rnn_bf = (unsigned short*)(W + 92274688);
    float*          cst    = (float*)(W + 100663296);
    float*          vn     = (float*)(W + 101187584);

    prep_vn<<<1, 1024, 0, stream>>>(v_att, norm_scalar, vn);
    cvt_f32_bf16<<<2048, 256, 0, stream>>>(W_ih, Wih_bf, 524288);
    cvt_f32_bf16<<<2048, 256, 0, stream>>>(W_hh, Whh_bf, 524288);
    cvt_f32_bf16<<<2048, 256, 0, stream>>>(context, ctx_bf, 524288);

    // xp = emb_table[tokens] @ W_ih^T + b_ih + b_hh   (fp32 out)
    gemm_bf16<true, false><<<dim3(32, 32), 256, 0, stream>>>(
        emb_table, Wih_bf, b_ih, b_hh, tokens, xp, MROWS, G4, ESZ);

    lstm0<<<64, 256, 0, stream>>>(xp, cst, rnn_out, rnn_bf);
    for (int t = 1; t < TDEC; t++) {
        lstm_step<<<dim3(32, 2), 256, 0, stream>>>(
            rnn_bf + (size_t)(t - 1) * BATCH * HSZ, Whh_bf,
            xp + (size_t)t * BATCH * G4, cst,
            rnn_out + (size_t)t * BATCH * HSZ,
            rnn_bf + (size_t)t * BATCH * HSZ);
    }

    // xp now dead: convert Wq/Wk into its region, then q/k projections (bf16 out)
    cvt_f32_bf16<<<512, 256, 0, stream>>>(Wq, Wq_bf, 131072);
    cvt_f32_bf16<<<512, 256, 0, stream>>>(Wk, Wk_bf, 131072);
    gemm_bf16<false, true><<<dim3(8, 32), 256, 0, stream>>>(
        rnn_bf, Wq_bf, nullptr, nullptr, nullptr, q_bf, MROWS, HSZ, HSZ);
    gemm_bf16<false, true><<<dim3(8, 32), 256, 0, stream>>>(
        ctx_bf, Wk_bf, nullptr, nullptr, nullptr, k_bf, MROWS, HSZ, CSZ);

    attn_kernel<<<BATCH * TDEC, 256, 0, stream>>>(
        q_bf, k_bf, vn, att_bias, ctx_bf, ctx_len, attn_out);
}